// Round 8
// baseline (235.265 us; speedup 1.0000x reference)
//
#include <hip/hip_runtime.h>
#include <hip/hip_bf16.h>
#include <cstdint>
#include <cstddef>

typedef __hip_bfloat16 bf16;
typedef short bf16x4 __attribute__((ext_vector_type(4)));
typedef short bf16x8 __attribute__((ext_vector_type(8)));
typedef float f32x4 __attribute__((ext_vector_type(4)));

#define LOG2E 1.44269504088896f

static constexpr int Bb = 2, S = 2048, D = 1024, H = 16, DH = 64;

struct TrueT  { static constexpr bool value = true;  };
struct FalseT { static constexpr bool value = false; };

__device__ inline short f2bf_bits(float f) {
  bf16 b = __float2bfloat16(f);
  short s;
  __builtin_memcpy(&s, &b, 2);
  return s;
}
__device__ inline float bfbits2f(short s) {
  uint32_t u = ((uint32_t)(uint16_t)s) << 16;
  float f;
  __builtin_memcpy(&f, &u, 4);
  return f;
}

// ---------------------------------------------------------------------------
// prep: both weight transposes + x cvt in ONE launch (grid-partitioned).
// ---------------------------------------------------------------------------
__global__ __launch_bounds__(256) void prep_kernel(
    const float* __restrict__ Wqkv, bf16* __restrict__ wqkvT,
    const float* __restrict__ Wout, bf16* __restrict__ woutT,
    const float* __restrict__ x, bf16* __restrict__ xbf) {
  const int blk = blockIdx.x;
  const int tid = threadIdx.x;
  if (blk < 4096) {
    __shared__ float t[32][33];
    const float* in;
    bf16* out;
    int R, C, bx, by;
    if (blk < 3072) { in = Wqkv; out = wqkvT; R = 1024; C = 3072; bx = blk % 96; by = blk / 96; }
    else            { in = Wout; out = woutT; R = 1024; C = 1024; bx = (blk - 3072) % 32; by = (blk - 3072) / 32; }
    int c0 = bx * 32, r0 = by * 32;
    int tx = tid & 31, ty = tid >> 5;
#pragma unroll
    for (int i = 0; i < 4; i++) {
      int r = ty + i * 8;
      t[r][tx] = in[(size_t)(r0 + r) * C + c0 + tx];
    }
    __syncthreads();
#pragma unroll
    for (int i = 0; i < 4; i++) {
      int c = ty + i * 8;
      out[(size_t)(c0 + c) * R + r0 + tx] = __float2bfloat16(t[tx][c]);
    }
  } else {
    size_t i = ((size_t)(blk - 4096) * 256 + tid) * 8;
    f32x4 a = *(const f32x4*)(x + i);
    f32x4 b = *(const f32x4*)(x + i + 4);
    bf16x8 v;
#pragma unroll
    for (int j = 0; j < 4; j++) { v[j] = f2bf_bits(a[j]); v[4 + j] = f2bf_bits(b[j]); }
    *(bf16x8*)((short*)xbf + i) = v;
  }
}

// ---------------------------------------------------------------------------
// GEMM1: qkv = x @ WqkvT^T + bqkv -> split Q/K [b,h,S,64], V^T [b,h,64,S].
// Q pre-scaled by 0.125*log2(e) in fp32 BEFORE bf16 rounding.
// T2 LDS swizzle (round 6): linear LDS dest + pre-swizzled global source
// column + XOR on the read granule. Residual 2-way alias is free.
// ---------------------------------------------------------------------------
__global__ __launch_bounds__(256) void gemm_qkv(
    const bf16* __restrict__ A, const bf16* __restrict__ Bt,
    const float* __restrict__ bias,
    bf16* __restrict__ Qb, bf16* __restrict__ Kb, bf16* __restrict__ Vtb) {
  constexpr int K = 1024;
  __shared__ __align__(16) short smA[128 * 32];
  __shared__ __align__(16) short smB[128 * 32];
  __shared__ __align__(16) short smE[4][16 * 72];

  const int tid = threadIdx.x;
  const int wave = tid >> 6, lane = tid & 63;
  const int quad = lane >> 4, l16 = lane & 15;
  const int m0 = blockIdx.y * 128, n0 = blockIdx.x * 128;
  const int wm = wave >> 1, wn = wave & 1;

  f32x4 acc[4][4];
#pragma unroll
  for (int i = 0; i < 4; i++)
#pragma unroll
    for (int j = 0; j < 4; j++) acc[i][j] = {0.f, 0.f, 0.f, 0.f};

  const int srow = lane >> 2;
  const int scol = ((lane & 3) ^ ((lane >> 3) & 3)) * 8;  // pre-swizzled src
  const int gsw = (l16 >> 1) & 3;                          // read-side XOR

  for (int k0 = 0; k0 < K; k0 += 32) {
#pragma unroll
    for (int half = 0; half < 2; half++) {
      int row = half * 64 + wave * 16 + srow;
      const bf16* ga = A + (size_t)(m0 + row) * K + k0 + scol;
      const bf16* gb = Bt + (size_t)(n0 + row) * K + k0 + scol;
      __builtin_amdgcn_global_load_lds(
          (const __attribute__((address_space(1))) void*)ga,
          (__attribute__((address_space(3))) void*)&smA[(half * 64 + wave * 16) * 32],
          16, 0, 0);
      __builtin_amdgcn_global_load_lds(
          (const __attribute__((address_space(1))) void*)gb,
          (__attribute__((address_space(3))) void*)&smB[(half * 64 + wave * 16) * 32],
          16, 0, 0);
    }
    __syncthreads();

    bf16x8 af[4], bf_[4];
#pragma unroll
    for (int mi = 0; mi < 4; mi++)
      af[mi] = *(const bf16x8*)&smA[(wm * 64 + mi * 16 + l16) * 32 + (quad ^ gsw) * 8];
#pragma unroll
    for (int ni = 0; ni < 4; ni++)
      bf_[ni] = *(const bf16x8*)&smB[(wn * 64 + ni * 16 + l16) * 32 + (quad ^ gsw) * 8];
#pragma unroll
    for (int mi = 0; mi < 4; mi++)
#pragma unroll
      for (int ni = 0; ni < 4; ni++)
        acc[mi][ni] = __builtin_amdgcn_mfma_f32_16x16x32_bf16(
            af[mi], bf_[ni], acc[mi][ni], 0, 0, 0);
    __syncthreads();
  }

  const int cs0 = n0 + wn * 64;
  const int h = cs0 / 192;
  const int rt = (cs0 >> 6) % 3;
  const int t0w = m0 + wm * 64;
  const int b = t0w >> 11, s0w = t0w & 2047;

  float bv[4];
#pragma unroll
  for (int ni = 0; ni < 4; ni++) bv[ni] = bias[cs0 + ni * 16 + l16];

  if (rt < 2) {
    const float qscale = (rt == 0) ? (0.125f * LOG2E) : 1.0f;
    bf16* dst = (rt == 0 ? Qb : Kb) + ((size_t)(b * H + h) * S + s0w) * 64;
    short* sE = &smE[wave][0];
    const int r8 = lane >> 2, s4 = lane & 3;
#pragma unroll
    for (int mi = 0; mi < 4; mi++) {
#pragma unroll
      for (int ni = 0; ni < 4; ni++)
#pragma unroll
        for (int r = 0; r < 4; r++)
          sE[(quad * 4 + r) * 72 + ni * 16 + l16] =
              f2bf_bits((acc[mi][ni][r] + bv[ni]) * qscale);
      asm volatile("s_waitcnt lgkmcnt(0)" ::: "memory");
      bf16x8 w0 = *(const bf16x8*)&sE[r8 * 72 + s4 * 16];
      bf16x8 w1 = *(const bf16x8*)&sE[r8 * 72 + s4 * 16 + 8];
      short* g = (short*)dst + (size_t)(mi * 16 + r8) * 64 + s4 * 16;
      *(bf16x8*)g = w0;
      *(bf16x8*)(g + 8) = w1;
      asm volatile("s_waitcnt lgkmcnt(0)" ::: "memory");
    }
  } else {
#pragma unroll
    for (int ni = 0; ni < 4; ni++) {
      const int dh = ni * 16 + l16;
#pragma unroll
      for (int mi = 0; mi < 4; mi++) {
        const int s0 = s0w + mi * 16 + quad * 4;
        size_t base = ((size_t)(b * H + h) * 64 + dh) * S + s0;
        bf16x4 vv;
#pragma unroll
        for (int r = 0; r < 4; r++) vv[r] = f2bf_bits(acc[mi][ni][r] + bv[ni]);
        *(bf16x4*)((short*)Vtb + base) = vv;
      }
    }
  }
}

// ---------------------------------------------------------------------------
// GEMM2: fp32 out, BN=64, LDS-staged epilogue. Same T2 swizzle as gemm_qkv.
// ---------------------------------------------------------------------------
__global__ __launch_bounds__(256) void gemm_out(
    const bf16* __restrict__ A, const bf16* __restrict__ Bt,
    const float* __restrict__ bias, float* __restrict__ C,
    int M, int N, int K) {
  constexpr int BN = 64, NF = 2;
  __shared__ __align__(16) short smA[128 * 32];
  __shared__ __align__(16) short smB[BN * 32];
  __shared__ __align__(16) float smEf[4][580];

  const int tid = threadIdx.x;
  const int wave = tid >> 6, lane = tid & 63;
  const int quad = lane >> 4, l16 = lane & 15;
  const int m0 = blockIdx.y * 128, n0 = blockIdx.x * BN;
  const int wm = wave >> 1, wn = wave & 1;

  f32x4 acc[4][NF];
#pragma unroll
  for (int i = 0; i < 4; i++)
#pragma unroll
    for (int j = 0; j < NF; j++) acc[i][j] = {0.f, 0.f, 0.f, 0.f};

  const int srow = lane >> 2;
  const int scol = ((lane & 3) ^ ((lane >> 3) & 3)) * 8;  // pre-swizzled src
  const int gsw = (l16 >> 1) & 3;                          // read-side XOR

  for (int k0 = 0; k0 < K; k0 += 32) {
#pragma unroll
    for (int half = 0; half < 2; half++) {
      int row = half * 64 + wave * 16 + srow;
      const bf16* ga = A + (size_t)(m0 + row) * K + k0 + scol;
      __builtin_amdgcn_global_load_lds(
          (const __attribute__((address_space(1))) void*)ga,
          (__attribute__((address_space(3))) void*)&smA[(half * 64 + wave * 16) * 32],
          16, 0, 0);
    }
    {
      int row = wave * 16 + srow;
      const bf16* gb = Bt + (size_t)(n0 + row) * K + k0 + scol;
      __builtin_amdgcn_global_load_lds(
          (const __attribute__((address_space(1))) void*)gb,
          (__attribute__((address_space(3))) void*)&smB[(wave * 16) * 32],
          16, 0, 0);
    }
    __syncthreads();

    bf16x8 af[4], bf_[NF];
#pragma unroll
    for (int mi = 0; mi < 4; mi++)
      af[mi] = *(const bf16x8*)&smA[(wm * 64 + mi * 16 + l16) * 32 + (quad ^ gsw) * 8];
#pragma unroll
    for (int ni = 0; ni < NF; ni++)
      bf_[ni] = *(const bf16x8*)&smB[(wn * 32 + ni * 16 + l16) * 32 + (quad ^ gsw) * 8];
#pragma unroll
    for (int mi = 0; mi < 4; mi++)
#pragma unroll
      for (int ni = 0; ni < NF; ni++)
        acc[mi][ni] = __builtin_amdgcn_mfma_f32_16x16x32_bf16(
            af[mi], bf_[ni], acc[mi][ni], 0, 0, 0);
    __syncthreads();
  }

  float bv[NF];
#pragma unroll
  for (int ni = 0; ni < NF; ni++) bv[ni] = bias[n0 + wn * 32 + ni * 16 + l16];

  float* sE = &smEf[wave][0];
#pragma unroll
  for (int mi = 0; mi < 4; mi++) {
#pragma unroll
    for (int ni = 0; ni < NF; ni++)
#pragma unroll
      for (int r = 0; r < 4; r++)
        sE[(quad * 4 + r) * 36 + ni * 16 + l16] = acc[mi][ni][r] + bv[ni];
    asm volatile("s_waitcnt lgkmcnt(0)" ::: "memory");
#pragma unroll
    for (int t = 0; t < 2; t++) {
      int slot = t * 64 + lane;
      int rr = slot >> 3, c4 = slot & 7;
      f32x4 v = *(const f32x4*)&sE[rr * 36 + c4 * 4];
      int row = m0 + wm * 64 + mi * 16 + rr;
      int col = n0 + wn * 32 + c4 * 4;
      *(f32x4*)&C[(size_t)row * N + col] = v;
    }
    asm volatile("s_waitcnt lgkmcnt(0)" ::: "memory");
  }
}

// ---------------------------------------------------------------------------
// Flash attention v13: round-7 core, but V is read DIRECTLY from L2 into
// registers (no smVt LDS staging): V fragments need no swizzle, are loaded
// at tile start so ~300cy L2 latency hides under QK^T+softmax, and LDS drops
// 42496->26112B. K keeps the dbuf global_load_lds pipeline. split=2 restores
// grid 1024 = exactly 4 blocks/CU (16 waves/CU, 2x round-7 TLP), perfectly
// balanced (p,31-p)x(sk) blocks, all co-resident. XCD-pinned bh for L2.
// ---------------------------------------------------------------------------
__global__ __launch_bounds__(256) void attn_kernel(
    const bf16* __restrict__ Qb, const bf16* __restrict__ Kb,
    const bf16* __restrict__ Vtb,
    bf16* __restrict__ Op0, bf16* __restrict__ Op1,
    float* __restrict__ lp0, float* __restrict__ lp1,
    bf16* __restrict__ Ofinal, int split) {
  const int blk = blockIdx.x;
  const int xcd = blk & 7;
  const int idx = blk >> 3;
  int sk, p, bh;
  if (split == 2) { bh = xcd + 8 * (idx / 32); int r = idx % 32; p = r & 15; sk = r >> 4; }
  else            { bh = xcd + 8 * (idx / 16); p = idx & 15; sk = 0; }
  const int h = bh & (H - 1), b = bh >> 4;
  const int tid = threadIdx.x;
  const int wave = tid >> 6, lane = tid & 63;
  const int quad = lane >> 4, l16 = lane & 15;

  bf16*  __restrict__ Op = sk ? Op1 : Op0;
  float* __restrict__ lp = sk ? lp1 : lp0;

  const bf16* Qh = Qb + (size_t)(b * H + h) * S * 64;
  const bf16* Kh = Kb + (size_t)(b * H + h) * S * 64;
  const bf16* Vth = Vtb + (size_t)(b * H + h) * 64 * S;

  __shared__ __align__(16) short smK[2][64 * 64];
  __shared__ __align__(16) short pLds[4][16][76];

  const int lrow = lane >> 3;
  const int lg = lane & 7;
  const int swz = l16 & 7;

  bf16x8 onesB;
#pragma unroll
  for (int j = 0; j < 8; j++) onesB[j] = (short)0x3F80;  // bf16 1.0

  // stage K tile `it2` into LDS buffer `bufi` (async; drained by barrier)
  auto stage = [&](int it2, int bufi) {
    const int kv0 = it2 * 64;
#pragma unroll
    for (int j = 0; j < 2; j++) {
      const int row = wave * 16 + j * 8 + lrow;
      const bf16* ks = Kh + (size_t)(kv0 + row) * 64 + (lg ^ (row & 7)) * 8;
      __builtin_amdgcn_global_load_lds(
          (const __attribute__((address_space(1))) void*)ks,
          (__attribute__((address_space(3))) void*)&smK[bufi][(wave * 16 + j * 8) * 64],
          16, 0, 0);
    }
  };

#pragma unroll
  for (int pass = 0; pass < 2; pass++) {
    const int qt = pass ? p : (31 - p);
    const int q0 = qt * 64 + wave * 16;
    const int qglob = q0 + l16;  // this lane's q (n-index in S^T)

    bf16x8 aQ[2];
#pragma unroll
    for (int kh = 0; kh < 2; kh++)
      aQ[kh] = *(const bf16x8*)(Qh + (size_t)(q0 + l16) * 64 + kh * 32 + quad * 8);

    f32x4 o[4];
#pragma unroll
    for (int dt = 0; dt < 4; dt++) o[dt] = {0.f, 0.f, 0.f, 0.f};
    f32x4 lacc = {0.f, 0.f, 0.f, 0.f};

    auto compute_tile = [&](int it2, int bufi, auto diag_tag) {
      constexpr bool DIAG = decltype(diag_tag)::value;
      const int kv0 = it2 * 64;

      // --- V fragments direct from L2 (no LDS): issued FIRST so latency
      // hides under QK^T + softmax. No swizzle needed.
      bf16x8 vf[4][2];
#pragma unroll
      for (int dt = 0; dt < 4; dt++)
#pragma unroll
        for (int k2 = 0; k2 < 2; k2++)
          vf[dt][k2] = *(const bf16x8*)(
              Vth + (size_t)(dt * 16 + l16) * S + kv0 + (k2 * 4 + quad) * 8);

      // --- S^T = K * Q^T (operand-swapped MFMA). z[nh] rows = kv, cols = q.
      f32x4 z[4];
      __builtin_amdgcn_s_setprio(1);
#pragma unroll
      for (int nh = 0; nh < 4; nh++) {
        const int row = nh * 16 + l16;
        f32x4 t = {0.f, 0.f, 0.f, 0.f};
#pragma unroll
        for (int kh = 0; kh < 2; kh++) {
          bf16x8 bK = *(const bf16x8*)&smK[bufi][row * 64 + ((kh * 4 + quad) ^ swz) * 8];
          t = __builtin_amdgcn_mfma_f32_16x16x32_bf16(bK, aQ[kh], t, 0, 0, 0);
        }
        z[nh] = t;
      }
      __builtin_amdgcn_s_setprio(0);

      // --- softmax numerator: lane holds k = kv0+nh*16+quad*4+r, q = qglob.
      // Q was pre-scaled by 0.125*log2e, so z IS the exp2 argument.
#pragma unroll
      for (int nh = 0; nh < 4; nh++) {
        bf16x4 pk;
#pragma unroll
        for (int r = 0; r < 4; r++) {
          float e = exp2f(z[nh][r]);
          if (DIAG) {
            const int kidx = kv0 + nh * 16 + quad * 4 + r;
            e = (kidx <= qglob) ? e : 0.f;
          }
          pk[r] = f2bf_bits(e);
        }
        // P[q=l16][k_local = nh*16+quad*4 .. +3] -> one 8B write
        *(bf16x4*)&pLds[wave][l16][nh * 16 + quad * 4] = pk;
      }

      asm volatile("s_waitcnt lgkmcnt(0)" ::: "memory");  // wave-local order

      // --- PV + l: aP = P in A-layout from pLds row l16; B = vf (registers).
      bf16x8 aP[2];
#pragma unroll
      for (int k2 = 0; k2 < 2; k2++)
        aP[k2] = *(const bf16x8*)&pLds[wave][l16][k2 * 32 + quad * 8];
      __builtin_amdgcn_s_setprio(1);
#pragma unroll
      for (int k2 = 0; k2 < 2; k2++)
        lacc = __builtin_amdgcn_mfma_f32_16x16x32_bf16(aP[k2], onesB, lacc, 0, 0, 0);
#pragma unroll
      for (int dt = 0; dt < 4; dt++)
#pragma unroll
        for (int k2 = 0; k2 < 2; k2++)
          o[dt] = __builtin_amdgcn_mfma_f32_16x16x32_bf16(aP[k2], vf[dt][k2], o[dt], 0, 0, 0);
      __builtin_amdgcn_s_setprio(0);
    };

    // --- K-dbuf kv loop: stage t+split into buf^1 during compute of t ---
    int it = sk;
    __syncthreads();               // previous pass's readers done with LDS
    if (it <= qt) stage(it, 0);
    __syncthreads();               // prologue drain (vmcnt(0) via barrier)
    int cur = 0;
    while (it <= qt) {
      const int next = it + split;
      if (next <= qt) stage(next, cur ^ 1);  // in flight during compute of `it`
      if (it == qt) compute_tile(it, cur, TrueT{});
      else          compute_tile(it, cur, FalseT{});
      __syncthreads();             // drains staged loads; readers done with cur
      cur ^= 1;
      it = next;
    }

    // --- epilogue: stage (o, or o/l) through pLds (stride 76) -> 32B stores
    short* pw = &pLds[wave][0][0];
    if (split > 1) {
      const size_t rowbase = (size_t)(b * H + h) * S + q0;
      if (l16 == 0) {
#pragma unroll
        for (int r = 0; r < 4; r++) lp[rowbase + quad * 4 + r] = lacc[r];
      }
#pragma unroll
      for (int dt = 0; dt < 4; dt++)
#pragma unroll
        for (int r = 0; r < 4; r++)
          pw[(quad * 4 + r) * 76 + dt * 16 + l16] = f2bf_bits(o[dt][r]);
      asm volatile("s_waitcnt lgkmcnt(0)" ::: "memory");
      {
        const int rl = lane >> 2, cq = lane & 3;
        bf16x8 w0 = *(const bf16x8*)&pw[rl * 76 + cq * 16];
        bf16x8 w1 = *(const bf16x8*)&pw[rl * 76 + cq * 16 + 8];
        short* g = (short*)Op + (rowbase + rl) * 64 + cq * 16;
        *(bf16x8*)g = w0;
        *(bf16x8*)(g + 8) = w1;
      }
      asm volatile("s_waitcnt lgkmcnt(0)" ::: "memory");
    } else {
      float inv[4];
#pragma unroll
      for (int r = 0; r < 4; r++) inv[r] = 1.f / lacc[r];
#pragma unroll
      for (int dt = 0; dt < 4; dt++)
#pragma unroll
        for (int r = 0; r < 4; r++)
          pw[(quad * 4 + r) * 76 + dt * 16 + l16] = f2bf_bits(o[dt][r] * inv[r]);
      asm volatile("s_waitcnt lgkmcnt(0)" ::: "memory");
      {
        const int rl = lane >> 2, cq = lane & 3;
        bf16x8 w0 = *(const bf16x8*)&pw[rl * 76 + cq * 16];
        bf16x8 w1 = *(const bf16x8*)&pw[rl * 76 + cq * 16 + 8];
        short* g = (short*)Ofinal + (size_t)(b * S + q0 + rl) * D + h * 64 + cq * 16;
        *(bf16x8*)g = w0;
        *(bf16x8*)(g + 8) = w1;
      }
      asm volatile("s_waitcnt lgkmcnt(0)" ::: "memory");
    }
  }
}

// ---------------------------------------------------------------------------
// Combine split-KV partials: O = (O0+O1)/(l0+l1), relayout to [b,s,h,dh]
// ---------------------------------------------------------------------------
__global__ __launch_bounds__(256) void attn_reduce(
    const bf16* __restrict__ O0, const bf16* __restrict__ O1,
    const float* __restrict__ l0, const float* __restrict__ l1,
    bf16* __restrict__ attnO) {
  int gid = blockIdx.x * 256 + threadIdx.x;
  int row = gid >> 3;
  int c8 = (gid & 7) * 8;
  float inv = 1.f / (l0[row] + l1[row]);
  bf16x8 a = *(const bf16x8*)((const short*)O0 + (size_t)row * 64 + c8);
  bf16x8 bb = *(const bf16x8*)((const short*)O1 + (size_t)row * 64 + c8);
  bf16x8 o;
#pragma unroll
  for (int j = 0; j < 8; j++)
    o[j] = f2bf_bits((bfbits2f(a[j]) + bfbits2f(bb[j])) * inv);
  int bh = row >> 11, q = row & 2047;
  int b = bh >> 4, h = bh & 15;
  *(bf16x8*)((short*)attnO + (((size_t)(b * S + q) * H + h) * 64 + c8)) = o;
}

// ---------------------------------------------------------------------------
extern "C" void kernel_launch(void* const* d_in, const int* in_sizes, int n_in,
                              void* d_out, int out_size, void* d_ws, size_t ws_size,
                              hipStream_t stream) {
  const float* x    = (const float*)d_in[0];
  const float* Wqkv = (const float*)d_in[1];
  const float* bqkv = (const float*)d_in[2];
  const float* Wout = (const float*)d_in[3];
  const float* bout = (const float*)d_in[4];
  float* out = (float*)d_out;

  char* ws = (char*)d_ws;
  const bool split2 = (ws_size >= 50855936);

  bf16* Qb  = (bf16*)(ws);
  bf16* Kb  = (bf16*)(ws + 8388608);
  bf16* Vtb = (bf16*)(ws + 16777216);
  bf16* xbf = (bf16*)(ws + 25165824);

  bf16 *Op0 = nullptr, *Op1 = nullptr, *attnO;
  float *lp0 = nullptr, *lp1 = nullptr;
  bf16 *wqkvT, *woutT;
  if (split2) {
    Op0   = (bf16*)(ws + 25165824);   // overlaps xbf (free after gemm_qkv)
    Op1   = (bf16*)(ws + 33554432);
    lp0   = (float*)(ws + 41943040);
    lp1   = (float*)(ws + 42205184);
    attnO = (bf16*)(ws + 8388608);    // overlaps Kb (free after attn)
    wqkvT = (bf16*)(ws + 42467328);
    woutT = (bf16*)(ws + 48758784);
  } else {
    attnO = (bf16*)(ws + 25165824);
    wqkvT = (bf16*)(ws + 33554432);
    woutT = (bf16*)(ws + 39845888);
  }

  prep_kernel<<<dim3(6144), 256, 0, stream>>>(Wqkv, wqkvT, Wout, woutT, x, xbf);

  gemm_qkv<<<dim3(3072 / 128, 4096 / 128), 256, 0, stream>>>(
      xbf, wqkvT, bqkv, Qb, Kb, Vtb);

  if (split2) {
    attn_kernel<<<dim3(1024), 256, 0, stream>>>(
        Qb, Kb, Vtb, Op0, Op1, lp0, lp1, nullptr, 2);
    attn_reduce<<<dim3(2048), 256, 0, stream>>>(Op0, Op1, lp0, lp1, attnO);
  } else {
    attn_kernel<<<dim3(512), 256, 0, stream>>>(
        Qb, Kb, Vtb, nullptr, nullptr, nullptr, nullptr, attnO, 1);
  }

  gemm_out<<<dim3(1024 / 64, 4096 / 128), 256, 0, stream>>>(
      attnO, woutT, bout, out, 4096, 1024, 1024);
}

// Round 9
// 183.519 us; speedup vs baseline: 1.2820x; 1.2820x over previous
//
#include <hip/hip_runtime.h>
#include <hip/hip_bf16.h>
#include <cstdint>
#include <cstddef>

typedef __hip_bfloat16 bf16;
typedef short bf16x4 __attribute__((ext_vector_type(4)));
typedef short bf16x8 __attribute__((ext_vector_type(8)));
typedef float f32x4 __attribute__((ext_vector_type(4)));

#define LOG2E 1.44269504088896f

static constexpr int Bb = 2, S = 2048, D = 1024, H = 16, DH = 64;

struct TrueT  { static constexpr bool value = true;  };
struct FalseT { static constexpr bool value = false; };

__device__ inline short f2bf_bits(float f) {
  bf16 b = __float2bfloat16(f);
  short s;
  __builtin_memcpy(&s, &b, 2);
  return s;
}
__device__ inline float bfbits2f(short s) {
  uint32_t u = ((uint32_t)(uint16_t)s) << 16;
  float f;
  __builtin_memcpy(&f, &u, 4);
  return f;
}

// ---------------------------------------------------------------------------
// prep: both weight transposes + x cvt in ONE launch (grid-partitioned).
// ---------------------------------------------------------------------------
__global__ __launch_bounds__(256) void prep_kernel(
    const float* __restrict__ Wqkv, bf16* __restrict__ wqkvT,
    const float* __restrict__ Wout, bf16* __restrict__ woutT,
    const float* __restrict__ x, bf16* __restrict__ xbf) {
  const int blk = blockIdx.x;
  const int tid = threadIdx.x;
  if (blk < 4096) {
    __shared__ float t[32][33];
    const float* in;
    bf16* out;
    int R, C, bx, by;
    if (blk < 3072) { in = Wqkv; out = wqkvT; R = 1024; C = 3072; bx = blk % 96; by = blk / 96; }
    else            { in = Wout; out = woutT; R = 1024; C = 1024; bx = (blk - 3072) % 32; by = (blk - 3072) / 32; }
    int c0 = bx * 32, r0 = by * 32;
    int tx = tid & 31, ty = tid >> 5;
#pragma unroll
    for (int i = 0; i < 4; i++) {
      int r = ty + i * 8;
      t[r][tx] = in[(size_t)(r0 + r) * C + c0 + tx];
    }
    __syncthreads();
#pragma unroll
    for (int i = 0; i < 4; i++) {
      int c = ty + i * 8;
      out[(size_t)(c0 + c) * R + r0 + tx] = __float2bfloat16(t[tx][c]);
    }
  } else {
    size_t i = ((size_t)(blk - 4096) * 256 + tid) * 8;
    f32x4 a = *(const f32x4*)(x + i);
    f32x4 b = *(const f32x4*)(x + i + 4);
    bf16x8 v;
#pragma unroll
    for (int j = 0; j < 4; j++) { v[j] = f2bf_bits(a[j]); v[4 + j] = f2bf_bits(b[j]); }
    *(bf16x8*)((short*)xbf + i) = v;
  }
}

// ---------------------------------------------------------------------------
// GEMM1: qkv = x @ WqkvT^T + bqkv -> split Q/K [b,h,S,64], V^T [b,h,64,S].
// Q pre-scaled by 0.125*log2(e) in fp32 BEFORE bf16 rounding.
// T2 LDS swizzle (round 6): linear LDS dest + pre-swizzled global source
// column + XOR on the read granule. Residual 2-way alias is free.
// ---------------------------------------------------------------------------
__global__ __launch_bounds__(256) void gemm_qkv(
    const bf16* __restrict__ A, const bf16* __restrict__ Bt,
    const float* __restrict__ bias,
    bf16* __restrict__ Qb, bf16* __restrict__ Kb, bf16* __restrict__ Vtb) {
  constexpr int K = 1024;
  __shared__ __align__(16) short smA[128 * 32];
  __shared__ __align__(16) short smB[128 * 32];
  __shared__ __align__(16) short smE[4][16 * 72];

  const int tid = threadIdx.x;
  const int wave = tid >> 6, lane = tid & 63;
  const int quad = lane >> 4, l16 = lane & 15;
  const int m0 = blockIdx.y * 128, n0 = blockIdx.x * 128;
  const int wm = wave >> 1, wn = wave & 1;

  f32x4 acc[4][4];
#pragma unroll
  for (int i = 0; i < 4; i++)
#pragma unroll
    for (int j = 0; j < 4; j++) acc[i][j] = {0.f, 0.f, 0.f, 0.f};

  const int srow = lane >> 2;
  const int scol = ((lane & 3) ^ ((lane >> 3) & 3)) * 8;  // pre-swizzled src
  const int gsw = (l16 >> 1) & 3;                          // read-side XOR

  for (int k0 = 0; k0 < K; k0 += 32) {
#pragma unroll
    for (int half = 0; half < 2; half++) {
      int row = half * 64 + wave * 16 + srow;
      const bf16* ga = A + (size_t)(m0 + row) * K + k0 + scol;
      const bf16* gb = Bt + (size_t)(n0 + row) * K + k0 + scol;
      __builtin_amdgcn_global_load_lds(
          (const __attribute__((address_space(1))) void*)ga,
          (__attribute__((address_space(3))) void*)&smA[(half * 64 + wave * 16) * 32],
          16, 0, 0);
      __builtin_amdgcn_global_load_lds(
          (const __attribute__((address_space(1))) void*)gb,
          (__attribute__((address_space(3))) void*)&smB[(half * 64 + wave * 16) * 32],
          16, 0, 0);
    }
    __syncthreads();

    bf16x8 af[4], bf_[4];
#pragma unroll
    for (int mi = 0; mi < 4; mi++)
      af[mi] = *(const bf16x8*)&smA[(wm * 64 + mi * 16 + l16) * 32 + (quad ^ gsw) * 8];
#pragma unroll
    for (int ni = 0; ni < 4; ni++)
      bf_[ni] = *(const bf16x8*)&smB[(wn * 64 + ni * 16 + l16) * 32 + (quad ^ gsw) * 8];
#pragma unroll
    for (int mi = 0; mi < 4; mi++)
#pragma unroll
      for (int ni = 0; ni < 4; ni++)
        acc[mi][ni] = __builtin_amdgcn_mfma_f32_16x16x32_bf16(
            af[mi], bf_[ni], acc[mi][ni], 0, 0, 0);
    __syncthreads();
  }

  const int cs0 = n0 + wn * 64;
  const int h = cs0 / 192;
  const int rt = (cs0 >> 6) % 3;
  const int t0w = m0 + wm * 64;
  const int b = t0w >> 11, s0w = t0w & 2047;

  float bv[4];
#pragma unroll
  for (int ni = 0; ni < 4; ni++) bv[ni] = bias[cs0 + ni * 16 + l16];

  if (rt < 2) {
    const float qscale = (rt == 0) ? (0.125f * LOG2E) : 1.0f;
    bf16* dst = (rt == 0 ? Qb : Kb) + ((size_t)(b * H + h) * S + s0w) * 64;
    short* sE = &smE[wave][0];
    const int r8 = lane >> 2, s4 = lane & 3;
#pragma unroll
    for (int mi = 0; mi < 4; mi++) {
#pragma unroll
      for (int ni = 0; ni < 4; ni++)
#pragma unroll
        for (int r = 0; r < 4; r++)
          sE[(quad * 4 + r) * 72 + ni * 16 + l16] =
              f2bf_bits((acc[mi][ni][r] + bv[ni]) * qscale);
      asm volatile("s_waitcnt lgkmcnt(0)" ::: "memory");
      bf16x8 w0 = *(const bf16x8*)&sE[r8 * 72 + s4 * 16];
      bf16x8 w1 = *(const bf16x8*)&sE[r8 * 72 + s4 * 16 + 8];
      short* g = (short*)dst + (size_t)(mi * 16 + r8) * 64 + s4 * 16;
      *(bf16x8*)g = w0;
      *(bf16x8*)(g + 8) = w1;
      asm volatile("s_waitcnt lgkmcnt(0)" ::: "memory");
    }
  } else {
#pragma unroll
    for (int ni = 0; ni < 4; ni++) {
      const int dh = ni * 16 + l16;
#pragma unroll
      for (int mi = 0; mi < 4; mi++) {
        const int s0 = s0w + mi * 16 + quad * 4;
        size_t base = ((size_t)(b * H + h) * 64 + dh) * S + s0;
        bf16x4 vv;
#pragma unroll
        for (int r = 0; r < 4; r++) vv[r] = f2bf_bits(acc[mi][ni][r] + bv[ni]);
        *(bf16x4*)((short*)Vtb + base) = vv;
      }
    }
  }
}

// ---------------------------------------------------------------------------
// GEMM2: fp32 out, BN=64, LDS-staged epilogue. Same T2 swizzle as gemm_qkv.
// ---------------------------------------------------------------------------
__global__ __launch_bounds__(256) void gemm_out(
    const bf16* __restrict__ A, const bf16* __restrict__ Bt,
    const float* __restrict__ bias, float* __restrict__ C,
    int M, int N, int K) {
  constexpr int BN = 64, NF = 2;
  __shared__ __align__(16) short smA[128 * 32];
  __shared__ __align__(16) short smB[BN * 32];
  __shared__ __align__(16) float smEf[4][580];

  const int tid = threadIdx.x;
  const int wave = tid >> 6, lane = tid & 63;
  const int quad = lane >> 4, l16 = lane & 15;
  const int m0 = blockIdx.y * 128, n0 = blockIdx.x * BN;
  const int wm = wave >> 1, wn = wave & 1;

  f32x4 acc[4][NF];
#pragma unroll
  for (int i = 0; i < 4; i++)
#pragma unroll
    for (int j = 0; j < NF; j++) acc[i][j] = {0.f, 0.f, 0.f, 0.f};

  const int srow = lane >> 2;
  const int scol = ((lane & 3) ^ ((lane >> 3) & 3)) * 8;  // pre-swizzled src
  const int gsw = (l16 >> 1) & 3;                          // read-side XOR

  for (int k0 = 0; k0 < K; k0 += 32) {
#pragma unroll
    for (int half = 0; half < 2; half++) {
      int row = half * 64 + wave * 16 + srow;
      const bf16* ga = A + (size_t)(m0 + row) * K + k0 + scol;
      __builtin_amdgcn_global_load_lds(
          (const __attribute__((address_space(1))) void*)ga,
          (__attribute__((address_space(3))) void*)&smA[(half * 64 + wave * 16) * 32],
          16, 0, 0);
    }
    {
      int row = wave * 16 + srow;
      const bf16* gb = Bt + (size_t)(n0 + row) * K + k0 + scol;
      __builtin_amdgcn_global_load_lds(
          (const __attribute__((address_space(1))) void*)gb,
          (__attribute__((address_space(3))) void*)&smB[(wave * 16) * 32],
          16, 0, 0);
    }
    __syncthreads();

    bf16x8 af[4], bf_[NF];
#pragma unroll
    for (int mi = 0; mi < 4; mi++)
      af[mi] = *(const bf16x8*)&smA[(wm * 64 + mi * 16 + l16) * 32 + (quad ^ gsw) * 8];
#pragma unroll
    for (int ni = 0; ni < NF; ni++)
      bf_[ni] = *(const bf16x8*)&smB[(wn * 32 + ni * 16 + l16) * 32 + (quad ^ gsw) * 8];
#pragma unroll
    for (int mi = 0; mi < 4; mi++)
#pragma unroll
      for (int ni = 0; ni < NF; ni++)
        acc[mi][ni] = __builtin_amdgcn_mfma_f32_16x16x32_bf16(
            af[mi], bf_[ni], acc[mi][ni], 0, 0, 0);
    __syncthreads();
  }

  float bv[NF];
#pragma unroll
  for (int ni = 0; ni < NF; ni++) bv[ni] = bias[n0 + wn * 32 + ni * 16 + l16];

  float* sE = &smEf[wave][0];
#pragma unroll
  for (int mi = 0; mi < 4; mi++) {
#pragma unroll
    for (int ni = 0; ni < NF; ni++)
#pragma unroll
      for (int r = 0; r < 4; r++)
        sE[(quad * 4 + r) * 36 + ni * 16 + l16] = acc[mi][ni][r] + bv[ni];
    asm volatile("s_waitcnt lgkmcnt(0)" ::: "memory");
#pragma unroll
    for (int t = 0; t < 2; t++) {
      int slot = t * 64 + lane;
      int rr = slot >> 3, c4 = slot & 7;
      f32x4 v = *(const f32x4*)&sE[rr * 36 + c4 * 4];
      int row = m0 + wm * 64 + mi * 16 + rr;
      int col = n0 + wn * 32 + c4 * 4;
      *(f32x4*)&C[(size_t)row * N + col] = v;
    }
    asm volatile("s_waitcnt lgkmcnt(0)" ::: "memory");
  }
}

// ---------------------------------------------------------------------------
// Flash attention v14: round-7 compute core (S^T, pre-scaled Q, diag-only
// mask, l via mfma(P,ones), XCD-pinned bh, setprio, K dbuf) with:
//  - SINGLE-buffered V staged JUST-IN-TIME: V[t] issued at tile top, its L2
//    latency hides under QK^T+softmax; before PV: counted s_waitcnt vmcnt(2)
//    (K[t+1] stays in flight - T4) + raw s_barrier (cross-wave visibility;
//    __syncthreads would drain vmcnt(0) and kill the K prefetch).
//  - LDS 42496 -> 34304B => 4 blocks/CU; split=2 paired grid 1024 = exactly
//    4/CU, one balanced cohort (2x round-7 waves in flight).
// ---------------------------------------------------------------------------
__global__ __launch_bounds__(256) void attn_kernel(
    const bf16* __restrict__ Qb, const bf16* __restrict__ Kb,
    const bf16* __restrict__ Vtb,
    bf16* __restrict__ Op0, bf16* __restrict__ Op1,
    float* __restrict__ lp0, float* __restrict__ lp1,
    bf16* __restrict__ Ofinal, int split) {
  const int blk = blockIdx.x;
  const int xcd = blk & 7;
  const int idx = blk >> 3;
  int sk, p, bh;
  if (split == 2) { bh = xcd + 8 * (idx / 32); int r = idx % 32; p = r & 15; sk = r >> 4; }
  else            { bh = xcd + 8 * (idx / 16); p = idx & 15; sk = 0; }
  const int h = bh & (H - 1), b = bh >> 4;
  const int tid = threadIdx.x;
  const int wave = tid >> 6, lane = tid & 63;
  const int quad = lane >> 4, l16 = lane & 15;

  bf16*  __restrict__ Op = sk ? Op1 : Op0;
  float* __restrict__ lp = sk ? lp1 : lp0;

  const bf16* Qh = Qb + (size_t)(b * H + h) * S * 64;
  const bf16* Kh = Kb + (size_t)(b * H + h) * S * 64;
  const bf16* Vth = Vtb + (size_t)(b * H + h) * 64 * S;

  __shared__ __align__(16) short smK[2][64 * 64];   // 16 KB (dbuf)
  __shared__ __align__(16) short smVt[64 * 64];     //  8 KB (single, JIT)
  __shared__ __align__(16) short pLds[4][16][76];   // 9.5 KB

  const int lrow = lane >> 3;
  const int lg = lane & 7;
  const int swz = l16 & 7;

  bf16x8 onesB;
#pragma unroll
  for (int j = 0; j < 8; j++) onesB[j] = (short)0x3F80;  // bf16 1.0

  auto stageK = [&](int it2, int bufi) {
    const int kv0 = it2 * 64;
#pragma unroll
    for (int j = 0; j < 2; j++) {
      const int row = wave * 16 + j * 8 + lrow;
      const bf16* ks = Kh + (size_t)(kv0 + row) * 64 + (lg ^ (row & 7)) * 8;
      __builtin_amdgcn_global_load_lds(
          (const __attribute__((address_space(1))) void*)ks,
          (__attribute__((address_space(3))) void*)&smK[bufi][(wave * 16 + j * 8) * 64],
          16, 0, 0);
    }
  };
  auto stageV = [&](int it2) {
    const int kv0 = it2 * 64;
#pragma unroll
    for (int j = 0; j < 2; j++) {
      const int row = wave * 16 + j * 8 + lrow;
      const bf16* vs = Vth + (size_t)row * S + kv0 + (lg ^ (row & 7)) * 8;
      __builtin_amdgcn_global_load_lds(
          (const __attribute__((address_space(1))) void*)vs,
          (__attribute__((address_space(3))) void*)&smVt[(wave * 16 + j * 8) * 64],
          16, 0, 0);
    }
  };

#pragma unroll
  for (int pass = 0; pass < 2; pass++) {
    const int qt = pass ? p : (31 - p);
    const int q0 = qt * 64 + wave * 16;
    const int qglob = q0 + l16;  // this lane's q (n-index in S^T)

    bf16x8 aQ[2];
#pragma unroll
    for (int kh = 0; kh < 2; kh++)
      aQ[kh] = *(const bf16x8*)(Qh + (size_t)(q0 + l16) * 64 + kh * 32 + quad * 8);

    f32x4 o[4];
#pragma unroll
    for (int dt = 0; dt < 4; dt++) o[dt] = {0.f, 0.f, 0.f, 0.f};
    f32x4 lacc = {0.f, 0.f, 0.f, 0.f};

    // One tile: QK^T from smK[bufi], softmax->pLds, then (after the V-wait
    // + barrier done by the caller) PV from smVt.
    auto qk_softmax = [&](int it2, int bufi, auto diag_tag) {
      constexpr bool DIAG = decltype(diag_tag)::value;
      const int kv0 = it2 * 64;
      f32x4 z[4];
      __builtin_amdgcn_s_setprio(1);
#pragma unroll
      for (int nh = 0; nh < 4; nh++) {
        const int row = nh * 16 + l16;
        f32x4 t = {0.f, 0.f, 0.f, 0.f};
#pragma unroll
        for (int kh = 0; kh < 2; kh++) {
          bf16x8 bK = *(const bf16x8*)&smK[bufi][row * 64 + ((kh * 4 + quad) ^ swz) * 8];
          t = __builtin_amdgcn_mfma_f32_16x16x32_bf16(bK, aQ[kh], t, 0, 0, 0);
        }
        z[nh] = t;
      }
      __builtin_amdgcn_s_setprio(0);

#pragma unroll
      for (int nh = 0; nh < 4; nh++) {
        bf16x4 pk;
#pragma unroll
        for (int r = 0; r < 4; r++) {
          float e = exp2f(z[nh][r]);
          if (DIAG) {
            const int kidx = kv0 + nh * 16 + quad * 4 + r;
            e = (kidx <= qglob) ? e : 0.f;
          }
          pk[r] = f2bf_bits(e);
        }
        *(bf16x4*)&pLds[wave][l16][nh * 16 + quad * 4] = pk;
      }
      asm volatile("s_waitcnt lgkmcnt(0)" ::: "memory");  // wave-local order
    };

    auto pv = [&]() {
      bf16x8 aP[2];
#pragma unroll
      for (int k2 = 0; k2 < 2; k2++)
        aP[k2] = *(const bf16x8*)&pLds[wave][l16][k2 * 32 + quad * 8];
      __builtin_amdgcn_s_setprio(1);
#pragma unroll
      for (int k2 = 0; k2 < 2; k2++)
        lacc = __builtin_amdgcn_mfma_f32_16x16x32_bf16(aP[k2], onesB, lacc, 0, 0, 0);
#pragma unroll
      for (int dt = 0; dt < 4; dt++) {
        const int row = dt * 16 + l16;
#pragma unroll
        for (int k2 = 0; k2 < 2; k2++) {
          bf16x8 bV = *(const bf16x8*)&smVt[row * 64 + ((k2 * 4 + quad) ^ swz) * 8];
          o[dt] = __builtin_amdgcn_mfma_f32_16x16x32_bf16(aP[k2], bV, o[dt], 0, 0, 0);
        }
      }
      __builtin_amdgcn_s_setprio(0);
    };

    // --- kv loop: K dbuf prefetch + JIT single-buffer V ---
    int it = sk;
    __syncthreads();               // prev pass's readers done with LDS
    if (it <= qt) stageK(it, 0);
    __syncthreads();               // prologue drain (vmcnt(0) via barrier)
    int cur = 0;
    while (it <= qt) {
      const int next = it + split;
      const bool hn = (next <= qt);
      stageV(it);                  // V[t]: oldest 2 vmem ops
      if (hn) stageK(next, cur ^ 1);  // K[t+1]: newest 2, stays in flight
      if (it == qt) qk_softmax(it, cur, TrueT{});
      else          qk_softmax(it, cur, FalseT{});
      // V landed? (counted: leave K[t+1] flying). Then cross-wave barrier.
      if (hn) { asm volatile("s_waitcnt vmcnt(2)" ::: "memory"); }
      else    { asm volatile("s_waitcnt vmcnt(0)" ::: "memory"); }
      __builtin_amdgcn_s_barrier();
      asm volatile("" ::: "memory");
      pv();
      __syncthreads();             // K[next] drained; smVt/smK readers done
      cur ^= 1;
      it = next;
    }

    // --- epilogue: stage through pLds (stride 76) -> 32B coalesced stores
    short* pw = &pLds[wave][0][0];
    if (split > 1) {
      const size_t rowbase = (size_t)(b * H + h) * S + q0;
      if (l16 == 0) {
#pragma unroll
        for (int r = 0; r < 4; r++) lp[rowbase + quad * 4 + r] = lacc[r];
      }
#pragma unroll
      for (int dt = 0; dt < 4; dt++)
#pragma unroll
        for (int r = 0; r < 4; r++)
          pw[(quad * 4 + r) * 76 + dt * 16 + l16] = f2bf_bits(o[dt][r]);
      asm volatile("s_waitcnt lgkmcnt(0)" ::: "memory");
      {
        const int rl = lane >> 2, cq = lane & 3;
        bf16x8 w0 = *(const bf16x8*)&pw[rl * 76 + cq * 16];
        bf16x8 w1 = *(const bf16x8*)&pw[rl * 76 + cq * 16 + 8];
        short* g = (short*)Op + (rowbase + rl) * 64 + cq * 16;
        *(bf16x8*)g = w0;
        *(bf16x8*)(g + 8) = w1;
      }
      asm volatile("s_waitcnt lgkmcnt(0)" ::: "memory");
    } else {
      float inv[4];
#pragma unroll
      for (int r = 0; r < 4; r++) inv[r] = 1.f / lacc[r];
#pragma unroll
      for (int dt = 0; dt < 4; dt++)
#pragma unroll
        for (int r = 0; r < 4; r++)
          pw[(quad * 4 + r) * 76 + dt * 16 + l16] = f2bf_bits(o[dt][r] * inv[r]);
      asm volatile("s_waitcnt lgkmcnt(0)" ::: "memory");
      {
        const int rl = lane >> 2, cq = lane & 3;
        bf16x8 w0 = *(const bf16x8*)&pw[rl * 76 + cq * 16];
        bf16x8 w1 = *(const bf16x8*)&pw[rl * 76 + cq * 16 + 8];
        short* g = (short*)Ofinal + (size_t)(b * S + q0 + rl) * D + h * 64 + cq * 16;
        *(bf16x8*)g = w0;
        *(bf16x8*)(g + 8) = w1;
      }
      asm volatile("s_waitcnt lgkmcnt(0)" ::: "memory");
    }
  }
}

// ---------------------------------------------------------------------------
// Combine split-KV partials: O = (O0+O1)/(l0+l1), relayout to [b,s,h,dh]
// ---------------------------------------------------------------------------
__global__ __launch_bounds__(256) void attn_reduce(
    const bf16* __restrict__ O0, const bf16* __restrict__ O1,
    const float* __restrict__ l0, const float* __restrict__ l1,
    bf16* __restrict__ attnO) {
  int gid = blockIdx.x * 256 + threadIdx.x;
  int row = gid >> 3;
  int c8 = (gid & 7) * 8;
  float inv = 1.f / (l0[row] + l1[row]);
  bf16x8 a = *(const bf16x8*)((const short*)O0 + (size_t)row * 64 + c8);
  bf16x8 bb = *(const bf16x8*)((const short*)O1 + (size_t)row * 64 + c8);
  bf16x8 o;
#pragma unroll
  for (int j = 0; j < 8; j++)
    o[j] = f2bf_bits((bfbits2f(a[j]) + bfbits2f(bb[j])) * inv);
  int bh = row >> 11, q = row & 2047;
  int b = bh >> 4, h = bh & 15;
  *(bf16x8*)((short*)attnO + (((size_t)(b * S + q) * H + h) * 64 + c8)) = o;
}

// ---------------------------------------------------------------------------
extern "C" void kernel_launch(void* const* d_in, const int* in_sizes, int n_in,
                              void* d_out, int out_size, void* d_ws, size_t ws_size,
                              hipStream_t stream) {
  const float* x    = (const float*)d_in[0];
  const float* Wqkv = (const float*)d_in[1];
  const float* bqkv = (const float*)d_in[2];
  const float* Wout = (const float*)d_in[3];
  const float* bout = (const float*)d_in[4];
  float* out = (float*)d_out;

  char* ws = (char*)d_ws;
  const bool split2 = (ws_size >= 50855936);

  bf16* Qb  = (bf16*)(ws);
  bf16* Kb  = (bf16*)(ws + 8388608);
  bf16* Vtb = (bf16*)(ws + 16777216);
  bf16* xbf = (bf16*)(ws + 25165824);

  bf16 *Op0 = nullptr, *Op1 = nullptr, *attnO;
  float *lp0 = nullptr, *lp1 = nullptr;
  bf16 *wqkvT, *woutT;
  if (split2) {
    Op0   = (bf16*)(ws + 25165824);   // overlaps xbf (free after gemm_qkv)
    Op1   = (bf16*)(ws + 33554432);
    lp0   = (float*)(ws + 41943040);
    lp1   = (float*)(ws + 42205184);
    attnO = (bf16*)(ws + 8388608);    // overlaps Kb (free after attn)
    wqkvT = (bf16*)(ws + 42467328);
    woutT = (bf16*)(ws + 48758784);
  } else {
    attnO = (bf16*)(ws + 25165824);
    wqkvT = (bf16*)(ws + 33554432);
    woutT = (bf16*)(ws + 39845888);
  }

  prep_kernel<<<dim3(6144), 256, 0, stream>>>(Wqkv, wqkvT, Wout, woutT, x, xbf);

  gemm_qkv<<<dim3(3072 / 128, 4096 / 128), 256, 0, stream>>>(
      xbf, wqkvT, bqkv, Qb, Kb, Vtb);

  if (split2) {
    attn_kernel<<<dim3(1024), 256, 0, stream>>>(
        Qb, Kb, Vtb, Op0, Op1, lp0, lp1, nullptr, 2);
    attn_reduce<<<dim3(2048), 256, 0, stream>>>(Op0, Op1, lp0, lp1, attnO);
  } else {
    attn_kernel<<<dim3(512), 256, 0, stream>>>(
        Qb, Kb, Vtb, nullptr, nullptr, nullptr, nullptr, attnO, 1);
  }

  gemm_out<<<dim3(1024 / 64, 4096 / 128), 256, 0, stream>>>(
      attnO, woutT, bout, out, 4096, 1024, 1024);
}

// Round 10
// 181.778 us; speedup vs baseline: 1.2942x; 1.0096x over previous
//
#include <hip/hip_runtime.h>
#include <hip/hip_bf16.h>
#include <cstdint>
#include <cstddef>

typedef __hip_bfloat16 bf16;
typedef short bf16x4 __attribute__((ext_vector_type(4)));
typedef short bf16x8 __attribute__((ext_vector_type(8)));
typedef float f32x4 __attribute__((ext_vector_type(4)));

#define LOG2E 1.44269504088896f

static constexpr int Bb = 2, S = 2048, D = 1024, H = 16, DH = 64;

struct TrueT  { static constexpr bool value = true;  };
struct FalseT { static constexpr bool value = false; };

__device__ inline short f2bf_bits(float f) {
  bf16 b = __float2bfloat16(f);
  short s;
  __builtin_memcpy(&s, &b, 2);
  return s;
}
__device__ inline float bfbits2f(short s) {
  uint32_t u = ((uint32_t)(uint16_t)s) << 16;
  float f;
  __builtin_memcpy(&f, &u, 4);
  return f;
}

// ---------------------------------------------------------------------------
// prep: both weight transposes + x cvt in ONE launch (grid-partitioned).
// ---------------------------------------------------------------------------
__global__ __launch_bounds__(256) void prep_kernel(
    const float* __restrict__ Wqkv, bf16* __restrict__ wqkvT,
    const float* __restrict__ Wout, bf16* __restrict__ woutT,
    const float* __restrict__ x, bf16* __restrict__ xbf) {
  const int blk = blockIdx.x;
  const int tid = threadIdx.x;
  if (blk < 4096) {
    __shared__ float t[32][33];
    const float* in;
    bf16* out;
    int R, C, bx, by;
    if (blk < 3072) { in = Wqkv; out = wqkvT; R = 1024; C = 3072; bx = blk % 96; by = blk / 96; }
    else            { in = Wout; out = woutT; R = 1024; C = 1024; bx = (blk - 3072) % 32; by = (blk - 3072) / 32; }
    int c0 = bx * 32, r0 = by * 32;
    int tx = tid & 31, ty = tid >> 5;
#pragma unroll
    for (int i = 0; i < 4; i++) {
      int r = ty + i * 8;
      t[r][tx] = in[(size_t)(r0 + r) * C + c0 + tx];
    }
    __syncthreads();
#pragma unroll
    for (int i = 0; i < 4; i++) {
      int c = ty + i * 8;
      out[(size_t)(c0 + c) * R + r0 + tx] = __float2bfloat16(t[tx][c]);
    }
  } else {
    size_t i = ((size_t)(blk - 4096) * 256 + tid) * 8;
    f32x4 a = *(const f32x4*)(x + i);
    f32x4 b = *(const f32x4*)(x + i + 4);
    bf16x8 v;
#pragma unroll
    for (int j = 0; j < 4; j++) { v[j] = f2bf_bits(a[j]); v[4 + j] = f2bf_bits(b[j]); }
    *(bf16x8*)((short*)xbf + i) = v;
  }
}

// ---------------------------------------------------------------------------
// GEMM1: qkv = x @ WqkvT^T + bqkv -> split Q/K [b,h,S,64], V^T [b,h,64,S].
// Q pre-scaled by 0.125*log2(e) in fp32 BEFORE bf16 rounding.
// T2 LDS swizzle (round 6) + DOUBLE-BUFFERED K-loop (round 10): stage K-step
// t+1 into buf^1 while computing t from buf -> one barrier per step, load
// latency hides under 16 MFMA + ds_reads. LDS 41KB -> 3 blocks/CU = grid.
// ---------------------------------------------------------------------------
__global__ __launch_bounds__(256) void gemm_qkv(
    const bf16* __restrict__ A, const bf16* __restrict__ Bt,
    const float* __restrict__ bias,
    bf16* __restrict__ Qb, bf16* __restrict__ Kb, bf16* __restrict__ Vtb) {
  constexpr int K = 1024;
  __shared__ __align__(16) short smA[2][128 * 32];
  __shared__ __align__(16) short smB[2][128 * 32];
  __shared__ __align__(16) short smE[4][16 * 72];

  const int tid = threadIdx.x;
  const int wave = tid >> 6, lane = tid & 63;
  const int quad = lane >> 4, l16 = lane & 15;
  const int m0 = blockIdx.y * 128, n0 = blockIdx.x * 128;
  const int wm = wave >> 1, wn = wave & 1;

  f32x4 acc[4][4];
#pragma unroll
  for (int i = 0; i < 4; i++)
#pragma unroll
    for (int j = 0; j < 4; j++) acc[i][j] = {0.f, 0.f, 0.f, 0.f};

  const int srow = lane >> 2;
  const int scol = ((lane & 3) ^ ((lane >> 3) & 3)) * 8;  // pre-swizzled src
  const int gsw = (l16 >> 1) & 3;                          // read-side XOR

  auto stage = [&](int k0, int bufi) {
#pragma unroll
    for (int half = 0; half < 2; half++) {
      int row = half * 64 + wave * 16 + srow;
      const bf16* ga = A + (size_t)(m0 + row) * K + k0 + scol;
      const bf16* gb = Bt + (size_t)(n0 + row) * K + k0 + scol;
      __builtin_amdgcn_global_load_lds(
          (const __attribute__((address_space(1))) void*)ga,
          (__attribute__((address_space(3))) void*)&smA[bufi][(half * 64 + wave * 16) * 32],
          16, 0, 0);
      __builtin_amdgcn_global_load_lds(
          (const __attribute__((address_space(1))) void*)gb,
          (__attribute__((address_space(3))) void*)&smB[bufi][(half * 64 + wave * 16) * 32],
          16, 0, 0);
    }
  };

  stage(0, 0);
  __syncthreads();                 // prologue drain
  int cur = 0;
  for (int k0 = 0; k0 < K; k0 += 32) {
    if (k0 + 32 < K) stage(k0 + 32, cur ^ 1);  // in flight during compute

    bf16x8 af[4], bf_[4];
#pragma unroll
    for (int mi = 0; mi < 4; mi++)
      af[mi] = *(const bf16x8*)&smA[cur][(wm * 64 + mi * 16 + l16) * 32 + (quad ^ gsw) * 8];
#pragma unroll
    for (int ni = 0; ni < 4; ni++)
      bf_[ni] = *(const bf16x8*)&smB[cur][(wn * 64 + ni * 16 + l16) * 32 + (quad ^ gsw) * 8];
#pragma unroll
    for (int mi = 0; mi < 4; mi++)
#pragma unroll
      for (int ni = 0; ni < 4; ni++)
        acc[mi][ni] = __builtin_amdgcn_mfma_f32_16x16x32_bf16(
            af[mi], bf_[ni], acc[mi][ni], 0, 0, 0);
    __syncthreads();               // drains staged loads; readers done w/ cur
    cur ^= 1;
  }

  const int cs0 = n0 + wn * 64;
  const int h = cs0 / 192;
  const int rt = (cs0 >> 6) % 3;
  const int t0w = m0 + wm * 64;
  const int b = t0w >> 11, s0w = t0w & 2047;

  float bv[4];
#pragma unroll
  for (int ni = 0; ni < 4; ni++) bv[ni] = bias[cs0 + ni * 16 + l16];

  if (rt < 2) {
    const float qscale = (rt == 0) ? (0.125f * LOG2E) : 1.0f;
    bf16* dst = (rt == 0 ? Qb : Kb) + ((size_t)(b * H + h) * S + s0w) * 64;
    short* sE = &smE[wave][0];
    const int r8 = lane >> 2, s4 = lane & 3;
#pragma unroll
    for (int mi = 0; mi < 4; mi++) {
#pragma unroll
      for (int ni = 0; ni < 4; ni++)
#pragma unroll
        for (int r = 0; r < 4; r++)
          sE[(quad * 4 + r) * 72 + ni * 16 + l16] =
              f2bf_bits((acc[mi][ni][r] + bv[ni]) * qscale);
      asm volatile("s_waitcnt lgkmcnt(0)" ::: "memory");
      bf16x8 w0 = *(const bf16x8*)&sE[r8 * 72 + s4 * 16];
      bf16x8 w1 = *(const bf16x8*)&sE[r8 * 72 + s4 * 16 + 8];
      short* g = (short*)dst + (size_t)(mi * 16 + r8) * 64 + s4 * 16;
      *(bf16x8*)g = w0;
      *(bf16x8*)(g + 8) = w1;
      asm volatile("s_waitcnt lgkmcnt(0)" ::: "memory");
    }
  } else {
#pragma unroll
    for (int ni = 0; ni < 4; ni++) {
      const int dh = ni * 16 + l16;
#pragma unroll
      for (int mi = 0; mi < 4; mi++) {
        const int s0 = s0w + mi * 16 + quad * 4;
        size_t base = ((size_t)(b * H + h) * 64 + dh) * S + s0;
        bf16x4 vv;
#pragma unroll
        for (int r = 0; r < 4; r++) vv[r] = f2bf_bits(acc[mi][ni][r] + bv[ni]);
        *(bf16x4*)((short*)Vtb + base) = vv;
      }
    }
  }
}

// ---------------------------------------------------------------------------
// GEMM2: fp32 out, BN=64, LDS-staged epilogue. T2 swizzle + dbuf K-loop.
// ---------------------------------------------------------------------------
__global__ __launch_bounds__(256) void gemm_out(
    const bf16* __restrict__ A, const bf16* __restrict__ Bt,
    const float* __restrict__ bias, float* __restrict__ C,
    int M, int N, int K) {
  constexpr int BN = 64, NF = 2;
  __shared__ __align__(16) short smA[2][128 * 32];
  __shared__ __align__(16) short smB[2][BN * 32];
  __shared__ __align__(16) float smEf[4][580];

  const int tid = threadIdx.x;
  const int wave = tid >> 6, lane = tid & 63;
  const int quad = lane >> 4, l16 = lane & 15;
  const int m0 = blockIdx.y * 128, n0 = blockIdx.x * BN;
  const int wm = wave >> 1, wn = wave & 1;

  f32x4 acc[4][NF];
#pragma unroll
  for (int i = 0; i < 4; i++)
#pragma unroll
    for (int j = 0; j < NF; j++) acc[i][j] = {0.f, 0.f, 0.f, 0.f};

  const int srow = lane >> 2;
  const int scol = ((lane & 3) ^ ((lane >> 3) & 3)) * 8;  // pre-swizzled src
  const int gsw = (l16 >> 1) & 3;                          // read-side XOR

  auto stage = [&](int k0, int bufi) {
#pragma unroll
    for (int half = 0; half < 2; half++) {
      int row = half * 64 + wave * 16 + srow;
      const bf16* ga = A + (size_t)(m0 + row) * K + k0 + scol;
      __builtin_amdgcn_global_load_lds(
          (const __attribute__((address_space(1))) void*)ga,
          (__attribute__((address_space(3))) void*)&smA[bufi][(half * 64 + wave * 16) * 32],
          16, 0, 0);
    }
    {
      int row = wave * 16 + srow;
      const bf16* gb = Bt + (size_t)(n0 + row) * K + k0 + scol;
      __builtin_amdgcn_global_load_lds(
          (const __attribute__((address_space(1))) void*)gb,
          (__attribute__((address_space(3))) void*)&smB[bufi][(wave * 16) * 32],
          16, 0, 0);
    }
  };

  stage(0, 0);
  __syncthreads();                 // prologue drain
  int cur = 0;
  for (int k0 = 0; k0 < K; k0 += 32) {
    if (k0 + 32 < K) stage(k0 + 32, cur ^ 1);

    bf16x8 af[4], bf_[NF];
#pragma unroll
    for (int mi = 0; mi < 4; mi++)
      af[mi] = *(const bf16x8*)&smA[cur][(wm * 64 + mi * 16 + l16) * 32 + (quad ^ gsw) * 8];
#pragma unroll
    for (int ni = 0; ni < NF; ni++)
      bf_[ni] = *(const bf16x8*)&smB[cur][(wn * 32 + ni * 16 + l16) * 32 + (quad ^ gsw) * 8];
#pragma unroll
    for (int mi = 0; mi < 4; mi++)
#pragma unroll
      for (int ni = 0; ni < NF; ni++)
        acc[mi][ni] = __builtin_amdgcn_mfma_f32_16x16x32_bf16(
            af[mi], bf_[ni], acc[mi][ni], 0, 0, 0);
    __syncthreads();
    cur ^= 1;
  }

  float bv[NF];
#pragma unroll
  for (int ni = 0; ni < NF; ni++) bv[ni] = bias[n0 + wn * 32 + ni * 16 + l16];

  float* sE = &smEf[wave][0];
#pragma unroll
  for (int mi = 0; mi < 4; mi++) {
#pragma unroll
    for (int ni = 0; ni < NF; ni++)
#pragma unroll
      for (int r = 0; r < 4; r++)
        sE[(quad * 4 + r) * 36 + ni * 16 + l16] = acc[mi][ni][r] + bv[ni];
    asm volatile("s_waitcnt lgkmcnt(0)" ::: "memory");
#pragma unroll
    for (int t = 0; t < 2; t++) {
      int slot = t * 64 + lane;
      int rr = slot >> 3, c4 = slot & 7;
      f32x4 v = *(const f32x4*)&sE[rr * 36 + c4 * 4];
      int row = m0 + wm * 64 + mi * 16 + rr;
      int col = n0 + wn * 32 + c4 * 4;
      *(f32x4*)&C[(size_t)row * N + col] = v;
    }
    asm volatile("s_waitcnt lgkmcnt(0)" ::: "memory");
  }
}

// ---------------------------------------------------------------------------
// Flash attention v14 (round-9, unchanged): S^T, pre-scaled Q, diag-only
// mask, l via mfma(P,ones), XCD-pinned bh, setprio, K dbuf, JIT single-buf V
// with counted vmcnt(2) + raw s_barrier before PV. 34.3KB LDS, 4 blocks/CU.
// ---------------------------------------------------------------------------
__global__ __launch_bounds__(256) void attn_kernel(
    const bf16* __restrict__ Qb, const bf16* __restrict__ Kb,
    const bf16* __restrict__ Vtb,
    bf16* __restrict__ Op0, bf16* __restrict__ Op1,
    float* __restrict__ lp0, float* __restrict__ lp1,
    bf16* __restrict__ Ofinal, int split) {
  const int blk = blockIdx.x;
  const int xcd = blk & 7;
  const int idx = blk >> 3;
  int sk, p, bh;
  if (split == 2) { bh = xcd + 8 * (idx / 32); int r = idx % 32; p = r & 15; sk = r >> 4; }
  else            { bh = xcd + 8 * (idx / 16); p = idx & 15; sk = 0; }
  const int h = bh & (H - 1), b = bh >> 4;
  const int tid = threadIdx.x;
  const int wave = tid >> 6, lane = tid & 63;
  const int quad = lane >> 4, l16 = lane & 15;

  bf16*  __restrict__ Op = sk ? Op1 : Op0;
  float* __restrict__ lp = sk ? lp1 : lp0;

  const bf16* Qh = Qb + (size_t)(b * H + h) * S * 64;
  const bf16* Kh = Kb + (size_t)(b * H + h) * S * 64;
  const bf16* Vth = Vtb + (size_t)(b * H + h) * 64 * S;

  __shared__ __align__(16) short smK[2][64 * 64];   // 16 KB (dbuf)
  __shared__ __align__(16) short smVt[64 * 64];     //  8 KB (single, JIT)
  __shared__ __align__(16) short pLds[4][16][76];   // 9.5 KB

  const int lrow = lane >> 3;
  const int lg = lane & 7;
  const int swz = l16 & 7;

  bf16x8 onesB;
#pragma unroll
  for (int j = 0; j < 8; j++) onesB[j] = (short)0x3F80;  // bf16 1.0

  auto stageK = [&](int it2, int bufi) {
    const int kv0 = it2 * 64;
#pragma unroll
    for (int j = 0; j < 2; j++) {
      const int row = wave * 16 + j * 8 + lrow;
      const bf16* ks = Kh + (size_t)(kv0 + row) * 64 + (lg ^ (row & 7)) * 8;
      __builtin_amdgcn_global_load_lds(
          (const __attribute__((address_space(1))) void*)ks,
          (__attribute__((address_space(3))) void*)&smK[bufi][(wave * 16 + j * 8) * 64],
          16, 0, 0);
    }
  };
  auto stageV = [&](int it2) {
    const int kv0 = it2 * 64;
#pragma unroll
    for (int j = 0; j < 2; j++) {
      const int row = wave * 16 + j * 8 + lrow;
      const bf16* vs = Vth + (size_t)row * S + kv0 + (lg ^ (row & 7)) * 8;
      __builtin_amdgcn_global_load_lds(
          (const __attribute__((address_space(1))) void*)vs,
          (__attribute__((address_space(3))) void*)&smVt[(wave * 16 + j * 8) * 64],
          16, 0, 0);
    }
  };

#pragma unroll
  for (int pass = 0; pass < 2; pass++) {
    const int qt = pass ? p : (31 - p);
    const int q0 = qt * 64 + wave * 16;
    const int qglob = q0 + l16;  // this lane's q (n-index in S^T)

    bf16x8 aQ[2];
#pragma unroll
    for (int kh = 0; kh < 2; kh++)
      aQ[kh] = *(const bf16x8*)(Qh + (size_t)(q0 + l16) * 64 + kh * 32 + quad * 8);

    f32x4 o[4];
#pragma unroll
    for (int dt = 0; dt < 4; dt++) o[dt] = {0.f, 0.f, 0.f, 0.f};
    f32x4 lacc = {0.f, 0.f, 0.f, 0.f};

    auto qk_softmax = [&](int it2, int bufi, auto diag_tag) {
      constexpr bool DIAG = decltype(diag_tag)::value;
      const int kv0 = it2 * 64;
      f32x4 z[4];
      __builtin_amdgcn_s_setprio(1);
#pragma unroll
      for (int nh = 0; nh < 4; nh++) {
        const int row = nh * 16 + l16;
        f32x4 t = {0.f, 0.f, 0.f, 0.f};
#pragma unroll
        for (int kh = 0; kh < 2; kh++) {
          bf16x8 bK = *(const bf16x8*)&smK[bufi][row * 64 + ((kh * 4 + quad) ^ swz) * 8];
          t = __builtin_amdgcn_mfma_f32_16x16x32_bf16(bK, aQ[kh], t, 0, 0, 0);
        }
        z[nh] = t;
      }
      __builtin_amdgcn_s_setprio(0);

#pragma unroll
      for (int nh = 0; nh < 4; nh++) {
        bf16x4 pk;
#pragma unroll
        for (int r = 0; r < 4; r++) {
          float e = exp2f(z[nh][r]);
          if (DIAG) {
            const int kidx = kv0 + nh * 16 + quad * 4 + r;
            e = (kidx <= qglob) ? e : 0.f;
          }
          pk[r] = f2bf_bits(e);
        }
        *(bf16x4*)&pLds[wave][l16][nh * 16 + quad * 4] = pk;
      }
      asm volatile("s_waitcnt lgkmcnt(0)" ::: "memory");  // wave-local order
    };

    auto pv = [&]() {
      bf16x8 aP[2];
#pragma unroll
      for (int k2 = 0; k2 < 2; k2++)
        aP[k2] = *(const bf16x8*)&pLds[wave][l16][k2 * 32 + quad * 8];
      __builtin_amdgcn_s_setprio(1);
#pragma unroll
      for (int k2 = 0; k2 < 2; k2++)
        lacc = __builtin_amdgcn_mfma_f32_16x16x32_bf16(aP[k2], onesB, lacc, 0, 0, 0);
#pragma unroll
      for (int dt = 0; dt < 4; dt++) {
        const int row = dt * 16 + l16;
#pragma unroll
        for (int k2 = 0; k2 < 2; k2++) {
          bf16x8 bV = *(const bf16x8*)&smVt[row * 64 + ((k2 * 4 + quad) ^ swz) * 8];
          o[dt] = __builtin_amdgcn_mfma_f32_16x16x32_bf16(aP[k2], bV, o[dt], 0, 0, 0);
        }
      }
      __builtin_amdgcn_s_setprio(0);
    };

    // --- kv loop: K dbuf prefetch + JIT single-buffer V ---
    int it = sk;
    __syncthreads();               // prev pass's readers done with LDS
    if (it <= qt) stageK(it, 0);
    __syncthreads();               // prologue drain (vmcnt(0) via barrier)
    int cur = 0;
    while (it <= qt) {
      const int next = it + split;
      const bool hn = (next <= qt);
      stageV(it);                  // V[t]: oldest 2 vmem ops
      if (hn) stageK(next, cur ^ 1);  // K[t+1]: newest 2, stays in flight
      if (it == qt) qk_softmax(it, cur, TrueT{});
      else          qk_softmax(it, cur, FalseT{});
      // V landed? (counted: leave K[t+1] flying). Then cross-wave barrier.
      if (hn) { asm volatile("s_waitcnt vmcnt(2)" ::: "memory"); }
      else    { asm volatile("s_waitcnt vmcnt(0)" ::: "memory"); }
      __builtin_amdgcn_s_barrier();
      asm volatile("" ::: "memory");
      pv();
      __syncthreads();             // K[next] drained; smVt/smK readers done
      cur ^= 1;
      it = next;
    }

    // --- epilogue: stage through pLds (stride 76) -> 32B coalesced stores
    short* pw = &pLds[wave][0][0];
    if (split > 1) {
      const size_t rowbase = (size_t)(b * H + h) * S + q0;
      if (l16 == 0) {
#pragma unroll
        for (int r = 0; r < 4; r++) lp[rowbase + quad * 4 + r] = lacc[r];
      }
#pragma unroll
      for (int dt = 0; dt < 4; dt++)
#pragma unroll
        for (int r = 0; r < 4; r++)
          pw[(quad * 4 + r) * 76 + dt * 16 + l16] = f2bf_bits(o[dt][r]);
      asm volatile("s_waitcnt lgkmcnt(0)" ::: "memory");
      {
        const int rl = lane >> 2, cq = lane & 3;
        bf16x8 w0 = *(const bf16x8*)&pw[rl * 76 + cq * 16];
        bf16x8 w1 = *(const bf16x8*)&pw[rl * 76 + cq * 16 + 8];
        short* g = (short*)Op + (rowbase + rl) * 64 + cq * 16;
        *(bf16x8*)g = w0;
        *(bf16x8*)(g + 8) = w1;
      }
      asm volatile("s_waitcnt lgkmcnt(0)" ::: "memory");
    } else {
      float inv[4];
#pragma unroll
      for (int r = 0; r < 4; r++) inv[r] = 1.f / lacc[r];
#pragma unroll
      for (int dt = 0; dt < 4; dt++)
#pragma unroll
        for (int r = 0; r < 4; r++)
          pw[(quad * 4 + r) * 76 + dt * 16 + l16] = f2bf_bits(o[dt][r] * inv[r]);
      asm volatile("s_waitcnt lgkmcnt(0)" ::: "memory");
      {
        const int rl = lane >> 2, cq = lane & 3;
        bf16x8 w0 = *(const bf16x8*)&pw[rl * 76 + cq * 16];
        bf16x8 w1 = *(const bf16x8*)&pw[rl * 76 + cq * 16 + 8];
        short* g = (short*)Ofinal + (size_t)(b * S + q0 + rl) * D + h * 64 + cq * 16;
        *(bf16x8*)g = w0;
        *(bf16x8*)(g + 8) = w1;
      }
      asm volatile("s_waitcnt lgkmcnt(0)" ::: "memory");
    }
  }
}

// ---------------------------------------------------------------------------
// Combine split-KV partials: O = (O0+O1)/(l0+l1), relayout to [b,s,h,dh]
// ---------------------------------------------------------------------------
__global__ __launch_bounds__(256) void attn_reduce(
    const bf16* __restrict__ O0, const bf16* __restrict__ O1,
    const float* __restrict__ l0, const float* __restrict__ l1,
    bf16* __restrict__ attnO) {
  int gid = blockIdx.x * 256 + threadIdx.x;
  int row = gid >> 3;
  int c8 = (gid & 7) * 8;
  float inv = 1.f / (l0[row] + l1[row]);
  bf16x8 a = *(const bf16x8*)((const short*)O0 + (size_t)row * 64 + c8);
  bf16x8 bb = *(const bf16x8*)((const short*)O1 + (size_t)row * 64 + c8);
  bf16x8 o;
#pragma unroll
  for (int j = 0; j < 8; j++)
    o[j] = f2bf_bits((bfbits2f(a[j]) + bfbits2f(bb[j])) * inv);
  int bh = row >> 11, q = row & 2047;
  int b = bh >> 4, h = bh & 15;
  *(bf16x8*)((short*)attnO + (((size_t)(b * S + q) * H + h) * 64 + c8)) = o;
}

// ---------------------------------------------------------------------------
extern "C" void kernel_launch(void* const* d_in, const int* in_sizes, int n_in,
                              void* d_out, int out_size, void* d_ws, size_t ws_size,
                              hipStream_t stream) {
  const float* x    = (const float*)d_in[0];
  const float* Wqkv = (const float*)d_in[1];
  const float* bqkv = (const float*)d_in[2];
  const float* Wout = (const float*)d_in[3];
  const float* bout = (const float*)d_in[4];
  float* out = (float*)d_out;

  char* ws = (char*)d_ws;
  const bool split2 = (ws_size >= 50855936);

  bf16* Qb  = (bf16*)(ws);
  bf16* Kb  = (bf16*)(ws + 8388608);
  bf16* Vtb = (bf16*)(ws + 16777216);
  bf16* xbf = (bf16*)(ws + 25165824);

  bf16 *Op0 = nullptr, *Op1 = nullptr, *attnO;
  float *lp0 = nullptr, *lp1 = nullptr;
  bf16 *wqkvT, *woutT;
  if (split2) {
    Op0   = (bf16*)(ws + 25165824);   // overlaps xbf (free after gemm_qkv)
    Op1   = (bf16*)(ws + 33554432);
    lp0   = (float*)(ws + 41943040);
    lp1   = (float*)(ws + 42205184);
    attnO = (bf16*)(ws + 8388608);    // overlaps Kb (free after attn)
    wqkvT = (bf16*)(ws + 42467328);
    woutT = (bf16*)(ws + 48758784);
  } else {
    attnO = (bf16*)(ws + 25165824);
    wqkvT = (bf16*)(ws + 33554432);
    woutT = (bf16*)(ws + 39845888);
  }

  prep_kernel<<<dim3(6144), 256, 0, stream>>>(Wqkv, wqkvT, Wout, woutT, x, xbf);

  gemm_qkv<<<dim3(3072 / 128, 4096 / 128), 256, 0, stream>>>(
      xbf, wqkvT, bqkv, Qb, Kb, Vtb);

  if (split2) {
    attn_kernel<<<dim3(1024), 256, 0, stream>>>(
        Qb, Kb, Vtb, Op0, Op1, lp0, lp1, nullptr, 2);
    attn_reduce<<<dim3(2048), 256, 0, stream>>>(Op0, Op1, lp0, lp1, attnO);
  } else {
    attn_kernel<<<dim3(512), 256, 0, stream>>>(
        Qb, Kb, Vtb, nullptr, nullptr, nullptr, nullptr, attnO, 1);
  }

  gemm_out<<<dim3(1024 / 64, 4096 / 128), 256, 0, stream>>>(
      attnO, woutT, bout, out, 4096, 1024, 1024);
}